// Round 2
// baseline (3441.971 us; speedup 1.0000x reference)
//
#include <hip/hip_runtime.h>
#include <hip/hip_bf16.h>

// Problem constants
constexpr int NB1    = 131073;   // num_bonds + 1 (row 131072 = zero sentinel)
constexpr int SENT   = 131072;
constexpr int NATOMS = 65536;
constexpr int AFD    = 133;
constexpr int CFD    = 147;
constexpr int DH     = 300;
constexpr int KO     = 433;      // AFD + DH
constexpr int GFD    = 2048;
constexpr int NMOLS  = 4096;
constexpr int OUTD   = DH + GFD; // 2348

constexpr int BM = 64, BN = 64, BK = 16;

// ---------- GEMM1: h = relu(f_ini @ W_i^T), bf16 out ------------------------
__global__ __launch_bounds__(256) void gemm1(const float* __restrict__ A,  // [NB1 x 147]
                                             const float* __restrict__ W,  // [300 x 147]
                                             __hip_bfloat16* __restrict__ h,
                                             int M) {
    __shared__ float As[BK][BM + 1];
    __shared__ float Bs[BK][BN + 1];
    const int tid = threadIdx.x;
    const int m0 = blockIdx.y * BM;
    const int n0 = blockIdx.x * BN;
    const int lc = tid & 15;   // k within tile
    const int lr = tid >> 4;   // 0..15
    const int tx = tid & 15, ty = tid >> 4;
    float acc[4][4] = {};
    for (int k0 = 0; k0 < CFD; k0 += BK) {
#pragma unroll
        for (int i = 0; i < 4; ++i) {
            int r = lr + 16 * i;
            int m = m0 + r, k = k0 + lc;
            float v = 0.f;
            if (m < M && k < CFD) v = A[(size_t)m * CFD + k];
            As[lc][r] = v;
        }
#pragma unroll
        for (int i = 0; i < 4; ++i) {
            int r = lr + 16 * i;
            int n = n0 + r, k = k0 + lc;
            float v = 0.f;
            if (n < DH && k < CFD) v = W[n * CFD + k];
            Bs[lc][r] = v;
        }
        __syncthreads();
#pragma unroll
        for (int kk = 0; kk < BK; ++kk) {
            float a[4], b[4];
#pragma unroll
            for (int i = 0; i < 4; ++i) a[i] = As[kk][ty * 4 + i];
#pragma unroll
            for (int j = 0; j < 4; ++j) b[j] = Bs[kk][tx * 4 + j];
#pragma unroll
            for (int i = 0; i < 4; ++i)
#pragma unroll
                for (int j = 0; j < 4; ++j) acc[i][j] += a[i] * b[j];
        }
        __syncthreads();
    }
#pragma unroll
    for (int i = 0; i < 4; ++i) {
        int m = m0 + ty * 4 + i;
        if (m >= M) continue;
#pragma unroll
        for (int j = 0; j < 4; ++j) {
            int n = n0 + tx * 4 + j;
            if (n >= DH) continue;
            float v = acc[i][j];
            h[(size_t)m * DH + n] = __float2bfloat16(v > 0.f ? v : 0.f);
        }
    }
}

// ---- GEMM2 (fused inp recompute):
//      hdst = relu( f_ini@W_i^T + (gather-sum_4 hsrc[mapping]) @ W_h^T ) -----
__global__ __launch_bounds__(256) void gemm2(const float* __restrict__ fini,      // [NB1 x 147]
                                             const __hip_bfloat16* __restrict__ hsrc,
                                             const int* __restrict__ mapping,    // [NB1 x 4]
                                             const float* __restrict__ Wi,       // [300 x 147]
                                             const float* __restrict__ Wh,       // [300 x 300]
                                             __hip_bfloat16* __restrict__ hdst,
                                             int M) {
    __shared__ float As[BK][BM + 1];
    __shared__ float Bs[BK][BN + 1];
    __shared__ int idx[BM][4];
    const int tid = threadIdx.x;
    const int m0 = blockIdx.y * BM;
    const int n0 = blockIdx.x * BN;
    const int lc = tid & 15;
    const int lr = tid >> 4;
    const int tx = tid & 15, ty = tid >> 4;
    {
        int r = tid >> 2, j = tid & 3;
        int m = m0 + r;
        int v = SENT;
        if (m < M) {
            int t = mapping[(size_t)m * 4 + j];
            v = (t < 0) ? SENT : t;
        }
        idx[r][j] = v;
    }
    __syncthreads();
    float acc[4][4] = {};
    // ---- phase 1: K over f_ini (147) with W_i ----
    for (int k0 = 0; k0 < CFD; k0 += BK) {
#pragma unroll
        for (int i = 0; i < 4; ++i) {
            int r = lr + 16 * i;
            int m = m0 + r, k = k0 + lc;
            float v = 0.f;
            if (m < M && k < CFD) v = fini[(size_t)m * CFD + k];
            As[lc][r] = v;
        }
#pragma unroll
        for (int i = 0; i < 4; ++i) {
            int r = lr + 16 * i;
            int n = n0 + r, k = k0 + lc;
            float v = 0.f;
            if (n < DH && k < CFD) v = Wi[n * CFD + k];
            Bs[lc][r] = v;
        }
        __syncthreads();
#pragma unroll
        for (int kk = 0; kk < BK; ++kk) {
            float a[4], b[4];
#pragma unroll
            for (int i = 0; i < 4; ++i) a[i] = As[kk][ty * 4 + i];
#pragma unroll
            for (int j = 0; j < 4; ++j) b[j] = Bs[kk][tx * 4 + j];
#pragma unroll
            for (int i = 0; i < 4; ++i)
#pragma unroll
                for (int j = 0; j < 4; ++j) acc[i][j] += a[i] * b[j];
        }
        __syncthreads();
    }
    // ---- phase 2: K over gathered h (300) with W_h ----
    for (int k0 = 0; k0 < DH; k0 += BK) {
#pragma unroll
        for (int i = 0; i < 4; ++i) {
            int r = lr + 16 * i;
            int k = k0 + lc;
            float v = 0.f;
            if (k < DH) {
                v = __bfloat162float(hsrc[(size_t)idx[r][0] * DH + k]) +
                    __bfloat162float(hsrc[(size_t)idx[r][1] * DH + k]) +
                    __bfloat162float(hsrc[(size_t)idx[r][2] * DH + k]) +
                    __bfloat162float(hsrc[(size_t)idx[r][3] * DH + k]);
            }
            As[lc][r] = v;
        }
#pragma unroll
        for (int i = 0; i < 4; ++i) {
            int r = lr + 16 * i;
            int n = n0 + r, k = k0 + lc;
            float v = 0.f;
            if (n < DH && k < DH) v = Wh[n * DH + k];
            Bs[lc][r] = v;
        }
        __syncthreads();
#pragma unroll
        for (int kk = 0; kk < BK; ++kk) {
            float a[4], b[4];
#pragma unroll
            for (int i = 0; i < 4; ++i) a[i] = As[kk][ty * 4 + i];
#pragma unroll
            for (int j = 0; j < 4; ++j) b[j] = Bs[kk][tx * 4 + j];
#pragma unroll
            for (int i = 0; i < 4; ++i)
#pragma unroll
                for (int j = 0; j < 4; ++j) acc[i][j] += a[i] * b[j];
        }
        __syncthreads();
    }
#pragma unroll
    for (int i = 0; i < 4; ++i) {
        int m = m0 + ty * 4 + i;
        if (m >= M) continue;
#pragma unroll
        for (int j = 0; j < 4; ++j) {
            int n = n0 + tx * 4 + j;
            if (n >= DH) continue;
            float v = acc[i][j];
            hdst[(size_t)m * DH + n] = __float2bfloat16(v > 0.f ? v : 0.f);
        }
    }
}

// ---- GEMM3: ah = relu(concat(atom_f, gather-sum_4 h[a2b]) @ W_o^T + b_o) ---
__global__ __launch_bounds__(256) void gemm3(const float* __restrict__ atomf, // [NATOMS x 133]
                                             const __hip_bfloat16* __restrict__ hsrc,
                                             const int* __restrict__ a2b,     // [NATOMS x 4]
                                             const float* __restrict__ W,     // [300 x 433]
                                             const float* __restrict__ bo,    // [300]
                                             float* __restrict__ ah) {
    __shared__ float As[BK][BM + 1];
    __shared__ float Bs[BK][BN + 1];
    __shared__ int idx[BM][4];
    const int tid = threadIdx.x;
    const int m0 = blockIdx.y * BM;
    const int n0 = blockIdx.x * BN;
    const int lc = tid & 15;
    const int lr = tid >> 4;
    const int tx = tid & 15, ty = tid >> 4;
    {
        int r = tid >> 2, j = tid & 3;
        int m = m0 + r;
        int t = a2b[(size_t)m * 4 + j];
        idx[r][j] = (t < 0) ? SENT : t;
    }
    __syncthreads();
    float acc[4][4] = {};
    for (int k0 = 0; k0 < KO; k0 += BK) {
#pragma unroll
        for (int i = 0; i < 4; ++i) {
            int r = lr + 16 * i;
            int m = m0 + r;
            int k = k0 + lc;
            float v = 0.f;
            if (k < AFD) {
                v = atomf[(size_t)m * AFD + k];
            } else if (k < KO) {
                int kh = k - AFD;
                v = __bfloat162float(hsrc[(size_t)idx[r][0] * DH + kh]) +
                    __bfloat162float(hsrc[(size_t)idx[r][1] * DH + kh]) +
                    __bfloat162float(hsrc[(size_t)idx[r][2] * DH + kh]) +
                    __bfloat162float(hsrc[(size_t)idx[r][3] * DH + kh]);
            }
            As[lc][r] = v;
        }
#pragma unroll
        for (int i = 0; i < 4; ++i) {
            int r = lr + 16 * i;
            int n = n0 + r, k = k0 + lc;
            float v = 0.f;
            if (n < DH && k < KO) v = W[n * KO + k];
            Bs[lc][r] = v;
        }
        __syncthreads();
#pragma unroll
        for (int kk = 0; kk < BK; ++kk) {
            float a[4], b[4];
#pragma unroll
            for (int i = 0; i < 4; ++i) a[i] = As[kk][ty * 4 + i];
#pragma unroll
            for (int j = 0; j < 4; ++j) b[j] = Bs[kk][tx * 4 + j];
#pragma unroll
            for (int i = 0; i < 4; ++i)
#pragma unroll
                for (int j = 0; j < 4; ++j) acc[i][j] += a[i] * b[j];
        }
        __syncthreads();
    }
#pragma unroll
    for (int i = 0; i < 4; ++i) {
        int m = m0 + ty * 4 + i;
#pragma unroll
        for (int j = 0; j < 4; ++j) {
            int n = n0 + tx * 4 + j;
            if (n >= DH) continue;
            float v = acc[i][j] + bo[n];
            ah[(size_t)m * DH + n] = v > 0.f ? v : 0.f;
        }
    }
}

// ---- molecule mean readout: out[mol][0:300] = mean_16 ah rows --------------
__global__ void mol_mean(const float* __restrict__ ah, float* __restrict__ out) {
    int t = blockIdx.x * blockDim.x + threadIdx.x;
    if (t >= NMOLS * DH) return;
    int mol = t / DH, n = t - mol * DH;
    float s = 0.f;
#pragma unroll
    for (int i = 0; i < 16; ++i) s += ah[((size_t)mol * 16 + i) * DH + n];
    out[(size_t)mol * OUTD + n] = s * (1.f / 16.f);
}

// ---- copy global features: out[mol][300:2348] = gf[mol] --------------------
__global__ void copy_gf(const float4* __restrict__ gf, float* __restrict__ out) {
    int t = blockIdx.x * blockDim.x + threadIdx.x;
    if (t >= NMOLS * (GFD / 4)) return;
    int mol = t >> 9;            // GFD/4 = 512 per mol
    int g4 = t & 511;
    float4 v = gf[t];
    *(float4*)(out + (size_t)mol * OUTD + DH + g4 * 4) = v;
}

extern "C" void kernel_launch(void* const* d_in, const int* in_sizes, int n_in,
                              void* d_out, int out_size, void* d_ws, size_t ws_size,
                              hipStream_t stream) {
    const float* atomf   = (const float*)d_in[0];
    const float* fini    = (const float*)d_in[1];
    const int*   a2b     = (const int*)d_in[2];
    const int*   mapping = (const int*)d_in[3];
    const float* gf      = (const float*)d_in[4];
    const float* W_i     = (const float*)d_in[5];
    const float* W_h     = (const float*)d_in[6];
    const float* W_o     = (const float*)d_in[7];
    const float* b_o     = (const float*)d_in[8];
    float* out = (float*)d_out;

    // Workspace: two bf16 h buffers (ping-pong), 78.64 MB each = 157.3 MB total.
    // ah (fp32, 78.64 MB) aliases h_b, which is dead by the time gemm3 runs.
    char* ws = (char*)d_ws;
    size_t S = ((size_t)NB1 * DH * sizeof(__hip_bfloat16) + 255) & ~(size_t)255;
    __hip_bfloat16* h_a = (__hip_bfloat16*)(ws);
    __hip_bfloat16* h_b = (__hip_bfloat16*)(ws + S);
    float* ah = (float*)(ws + S);  // alias h_b

    dim3 blk(256);
    dim3 gBond((DH + BN - 1) / BN, (NB1 + BM - 1) / BM);     // 5 x 2049
    dim3 gAtom((DH + BN - 1) / BN, NATOMS / BM);             // 5 x 1024

    gemm1<<<gBond, blk, 0, stream>>>(fini, W_i, h_a, NB1);
    gemm2<<<gBond, blk, 0, stream>>>(fini, h_a, mapping, W_i, W_h, h_b, NB1);
    gemm2<<<gBond, blk, 0, stream>>>(fini, h_b, mapping, W_i, W_h, h_a, NB1);
    gemm3<<<gAtom, blk, 0, stream>>>(atomf, h_a, a2b, W_o, b_o, ah);
    mol_mean<<<(NMOLS * DH + 255) / 256, 256, 0, stream>>>(ah, out);
    copy_gf<<<(NMOLS * GFD / 4 + 255) / 256, 256, 0, stream>>>((const float4*)gf, out);
}

// Round 3
// 670.670 us; speedup vs baseline: 5.1321x; 5.1321x over previous
//
#include <hip/hip_runtime.h>

typedef short bf16x8 __attribute__((ext_vector_type(8)));
typedef float f32x4 __attribute__((ext_vector_type(4)));

constexpr int NB1    = 131073;   // num_bonds + 1 (row 131072 = zero sentinel)
constexpr int SENT   = 131072;
constexpr int NATOMS = 65536;
constexpr int AFD    = 133;
constexpr int CFD    = 147;
constexpr int DH     = 300;
constexpr int GFD    = 2048;
constexpr int NMOLS  = 4096;
constexpr int OUTD   = DH + GFD; // 2348
constexpr int HS     = 320;      // h row stride (bf16), also padded N
constexpr int KP1    = 160;      // padded CFD (and padded AFD for gemm3)
constexpr int KP2    = 320;      // padded DH

__device__ __forceinline__ unsigned short f2b(float f) {
    unsigned u = __float_as_uint(f);
    u += 0x7fffu + ((u >> 16) & 1u);
    return (unsigned short)(u >> 16);
}
__device__ __forceinline__ unsigned pairsum4(unsigned a, unsigned b, unsigned c, unsigned d) {
    float lo = __uint_as_float(a << 16) + __uint_as_float(b << 16) +
               __uint_as_float(c << 16) + __uint_as_float(d << 16);
    float hi = __uint_as_float(a & 0xffff0000u) + __uint_as_float(b & 0xffff0000u) +
               __uint_as_float(c & 0xffff0000u) + __uint_as_float(d & 0xffff0000u);
    return ((unsigned)f2b(hi) << 16) | (unsigned)f2b(lo);
}

// Bs[kh][n][8] <- Wp[n][k0 + kh*8 ..], 64B contiguous per n
__device__ __forceinline__ void stage_B(short* Bs, const unsigned short* __restrict__ Wp,
                                        int stride, int k0, int tid) {
#pragma unroll
    for (int rep = 0; rep < 2; ++rep) {
        int n = tid + rep * 256;
        if (n < KP2) {
            const uint4* src = (const uint4*)(Wp + (size_t)n * stride + k0);
            uint4 c0 = src[0], c1 = src[1], c2 = src[2], c3 = src[3];
            *(uint4*)&Bs[(0 * KP2 + n) * 8] = c0;
            *(uint4*)&Bs[(1 * KP2 + n) * 8] = c1;
            *(uint4*)&Bs[(2 * KP2 + n) * 8] = c2;
            *(uint4*)&Bs[(3 * KP2 + n) * 8] = c3;
        }
    }
}

__device__ __forceinline__ void mfma_step(const short* As, const short* Bs, int w, int lane,
                                          f32x4 (&acc)[4][5]) {
    const int ml = lane & 15, kl = lane >> 4;
    bf16x8 af[4], bg[5];
#pragma unroll
    for (int mt = 0; mt < 4; ++mt)
        af[mt] = *(const bf16x8*)&As[(kl * 64 + mt * 16 + ml) * 8];
#pragma unroll
    for (int nt = 0; nt < 5; ++nt)
        bg[nt] = *(const bf16x8*)&Bs[(kl * KP2 + w * 80 + nt * 16 + ml) * 8];
#pragma unroll
    for (int mt = 0; mt < 4; ++mt)
#pragma unroll
        for (int nt = 0; nt < 5; ++nt)
            acc[mt][nt] = __builtin_amdgcn_mfma_f32_16x16x32_bf16(af[mt], bg[nt], acc[mt][nt], 0, 0, 0);
}

// ---- bond GEMM: hdst = relu( fini@WiP^T  [+ (gather-sum_4 hsrc[mapping]) @ WhP^T] ) ----
__global__ __launch_bounds__(256, 2) void bond_gemm(
    const float* __restrict__ fini,           // [NB1][147] fp32
    const unsigned short* __restrict__ hsrc,  // [NB1][HS] bf16 bits
    const int* __restrict__ mapping,          // [NB1][4]
    const unsigned short* __restrict__ WiP,   // [320][160] bf16
    const unsigned short* __restrict__ WhP,   // [320][320] bf16
    unsigned short* __restrict__ hdst,        // [NB1][HS] bf16
    int do_msg)
{
    __shared__ __align__(16) short As[4 * 64 * 8];    //  4 KB
    __shared__ __align__(16) short Bs[4 * KP2 * 8];   // 20 KB
    __shared__ int idx[64][4];
    const int tid  = threadIdx.x;
    const int m0   = blockIdx.x * 64;
    const int lane = tid & 63;
    const int w    = tid >> 6;
    const int sr   = tid & 63;   // staging row
    const int skh  = tid >> 6;   // staging k-half (0..3)

    if (do_msg) {
        int r = tid >> 2, j = tid & 3;
        int m = m0 + r;
        int v = SENT;
        if (m < NB1) { int t = mapping[(size_t)m * 4 + j]; v = (t < 0) ? SENT : t; }
        idx[r][j] = v;
    }

    f32x4 acc[4][5];
#pragma unroll
    for (int mt = 0; mt < 4; ++mt)
#pragma unroll
        for (int nt = 0; nt < 5; ++nt) acc[mt][nt] = (f32x4){0.f, 0.f, 0.f, 0.f};

    // ---- phase 1: fini (fp32, K=147 pad 160) @ WiP ----
    for (int k0 = 0; k0 < KP1; k0 += 32) {
        {
            int m = m0 + sr;
            const float* src = fini + (size_t)m * CFD;
            float v[8];
#pragma unroll
            for (int j = 0; j < 8; ++j) {
                int k = k0 + skh * 8 + j;
                v[j] = (m < NB1 && k < CFD) ? src[k] : 0.f;
            }
            union { short s[8]; bf16x8 x; } u;
#pragma unroll
            for (int j = 0; j < 8; ++j) u.s[j] = (short)f2b(v[j]);
            *(bf16x8*)&As[(skh * 64 + sr) * 8] = u.x;
        }
        stage_B(Bs, WiP, KP1, k0, tid);
        __syncthreads();
        mfma_step(As, Bs, w, lane, acc);
        __syncthreads();
    }

    // ---- phase 2: gathered h (bf16, K=300 pad 320) @ WhP ----
    if (do_msg) {
        for (int k0 = 0; k0 < KP2; k0 += 32) {
            {
                int koff = k0 + skh * 8;
                uint4 a = *(const uint4*)(hsrc + (size_t)idx[sr][0] * HS + koff);
                uint4 b = *(const uint4*)(hsrc + (size_t)idx[sr][1] * HS + koff);
                uint4 c = *(const uint4*)(hsrc + (size_t)idx[sr][2] * HS + koff);
                uint4 d = *(const uint4*)(hsrc + (size_t)idx[sr][3] * HS + koff);
                uint4 o;
                o.x = pairsum4(a.x, b.x, c.x, d.x);
                o.y = pairsum4(a.y, b.y, c.y, d.y);
                o.z = pairsum4(a.z, b.z, c.z, d.z);
                o.w = pairsum4(a.w, b.w, c.w, d.w);
                *(uint4*)&As[(skh * 64 + sr) * 8] = o;
            }
            stage_B(Bs, WhP, KP2, k0, tid);
            __syncthreads();
            mfma_step(As, Bs, w, lane, acc);
            __syncthreads();
        }
    }

    // ---- epilogue: relu -> bf16, write all 320 cols (pad cols get relu(0)=0) ----
    const int ml = lane & 15, kl = lane >> 4;
#pragma unroll
    for (int mt = 0; mt < 4; ++mt) {
#pragma unroll
        for (int reg = 0; reg < 4; ++reg) {
            int mm = m0 + mt * 16 + kl * 4 + reg;
            if (mm < NB1) {
#pragma unroll
                for (int nt = 0; nt < 5; ++nt) {
                    int n = w * 80 + nt * 16 + ml;
                    float v = acc[mt][nt][reg];
                    hdst[(size_t)mm * HS + n] = f2b(v > 0.f ? v : 0.f);
                }
            }
        }
    }
}

// ---- atom GEMM + fused molecule mean:
//      out[mol][0:300] = mean_16 relu(concat(atomf, gather-sum_4 h[a2b]) @ Wo^T + bo) ----
__global__ __launch_bounds__(256, 2) void atom_gemm(
    const float* __restrict__ atomf,          // [NATOMS][133] fp32
    const unsigned short* __restrict__ hsrc,  // [NB1][HS] bf16
    const int* __restrict__ a2b,              // [NATOMS][4]
    const unsigned short* __restrict__ WoA,   // [320][160] bf16 (Wo cols 0..132)
    const unsigned short* __restrict__ WoB,   // [320][320] bf16 (Wo cols 133..432)
    const float* __restrict__ bo,             // [300]
    float* __restrict__ out)                  // [NMOLS][OUTD]
{
    __shared__ __align__(16) short As[4 * 64 * 8];
    __shared__ __align__(16) short Bs[4 * KP2 * 8];
    __shared__ int idx[64][4];
    const int tid  = threadIdx.x;
    const int m0   = blockIdx.x * 64;
    const int lane = tid & 63;
    const int w    = tid >> 6;
    const int sr   = tid & 63;
    const int skh  = tid >> 6;

    {
        int r = tid >> 2, j = tid & 3;
        int t = a2b[(size_t)(m0 + r) * 4 + j];
        idx[r][j] = (t < 0) ? SENT : t;
    }

    f32x4 acc[4][5];
#pragma unroll
    for (int mt = 0; mt < 4; ++mt)
#pragma unroll
        for (int nt = 0; nt < 5; ++nt) acc[mt][nt] = (f32x4){0.f, 0.f, 0.f, 0.f};

    // ---- phase A: atomf (fp32, K=133 pad 160) @ WoA ----
    for (int k0 = 0; k0 < KP1; k0 += 32) {
        {
            const float* src = atomf + (size_t)(m0 + sr) * AFD;
            float v[8];
#pragma unroll
            for (int j = 0; j < 8; ++j) {
                int k = k0 + skh * 8 + j;
                v[j] = (k < AFD) ? src[k] : 0.f;
            }
            union { short s[8]; bf16x8 x; } u;
#pragma unroll
            for (int j = 0; j < 8; ++j) u.s[j] = (short)f2b(v[j]);
            *(bf16x8*)&As[(skh * 64 + sr) * 8] = u.x;
        }
        stage_B(Bs, WoA, KP1, k0, tid);
        __syncthreads();
        mfma_step(As, Bs, w, lane, acc);
        __syncthreads();
    }

    // ---- phase B: gathered h (K=300 pad 320) @ WoB ----
    for (int k0 = 0; k0 < KP2; k0 += 32) {
        {
            int koff = k0 + skh * 8;
            uint4 a = *(const uint4*)(hsrc + (size_t)idx[sr][0] * HS + koff);
            uint4 b = *(const uint4*)(hsrc + (size_t)idx[sr][1] * HS + koff);
            uint4 c = *(const uint4*)(hsrc + (size_t)idx[sr][2] * HS + koff);
            uint4 d = *(const uint4*)(hsrc + (size_t)idx[sr][3] * HS + koff);
            uint4 o;
            o.x = pairsum4(a.x, b.x, c.x, d.x);
            o.y = pairsum4(a.y, b.y, c.y, d.y);
            o.z = pairsum4(a.z, b.z, c.z, d.z);
            o.w = pairsum4(a.w, b.w, c.w, d.w);
            *(uint4*)&As[(skh * 64 + sr) * 8] = o;
        }
        stage_B(Bs, WoB, KP2, k0, tid);
        __syncthreads();
        mfma_step(As, Bs, w, lane, acc);
        __syncthreads();
    }

    // ---- epilogue: bias + relu + 16-row (one molecule per m-tile) mean -> out ----
    const int ml = lane & 15, kl = lane >> 4;
#pragma unroll
    for (int mt = 0; mt < 4; ++mt) {
        int mol = blockIdx.x * 4 + mt;
#pragma unroll
        for (int nt = 0; nt < 5; ++nt) {
            int n = w * 80 + nt * 16 + ml;
            float bias = (n < DH) ? bo[n] : 0.f;
            float s = 0.f;
#pragma unroll
            for (int reg = 0; reg < 4; ++reg) {
                float v = acc[mt][nt][reg] + bias;
                s += (v > 0.f ? v : 0.f);
            }
            s += __shfl_down(s, 32, 64);
            s += __shfl_down(s, 16, 64);
            if (kl == 0 && n < DH) out[(size_t)mol * OUTD + n] = s * (1.f / 16.f);
        }
    }
}

// ---- weight prep: fp32 -> padded bf16 ----
__global__ void prep_w(const float* __restrict__ Wi, const float* __restrict__ Wh,
                       const float* __restrict__ Wo, unsigned short* __restrict__ wb) {
    int t = blockIdx.x * blockDim.x + threadIdx.x;
    if (t >= 307200) return;
    float v = 0.f;
    if (t < 51200) {                       // WiP [320][160]
        int n = t / 160, k = t % 160;
        if (n < DH && k < CFD) v = Wi[n * CFD + k];
    } else if (t < 153600) {               // WhP [320][320]
        int q = t - 51200; int n = q / 320, k = q % 320;
        if (n < DH && k < DH) v = Wh[n * DH + k];
    } else if (t < 204800) {               // WoA [320][160]
        int q = t - 153600; int n = q / 160, k = q % 160;
        if (n < DH && k < AFD) v = Wo[n * 433 + k];
    } else {                               // WoB [320][320]
        int q = t - 204800; int n = q / 320, k = q % 320;
        if (n < DH && k < DH) v = Wo[n * 433 + AFD + k];
    }
    wb[t] = f2b(v);
}

// ---- copy global features: out[mol][300:2348] = gf[mol] ----
__global__ void copy_gf(const float4* __restrict__ gf, float* __restrict__ out) {
    int t = blockIdx.x * blockDim.x + threadIdx.x;
    if (t >= NMOLS * (GFD / 4)) return;
    int mol = t >> 9;            // GFD/4 = 512 per mol
    int g4 = t & 511;
    float4 v = gf[t];
    *(float4*)(out + (size_t)mol * OUTD + DH + g4 * 4) = v;
}

extern "C" void kernel_launch(void* const* d_in, const int* in_sizes, int n_in,
                              void* d_out, int out_size, void* d_ws, size_t ws_size,
                              hipStream_t stream) {
    const float* atomf   = (const float*)d_in[0];
    const float* fini    = (const float*)d_in[1];
    const int*   a2b     = (const int*)d_in[2];
    const int*   mapping = (const int*)d_in[3];
    const float* gf      = (const float*)d_in[4];
    const float* W_i     = (const float*)d_in[5];
    const float* W_h     = (const float*)d_in[6];
    const float* W_o     = (const float*)d_in[7];
    const float* b_o     = (const float*)d_in[8];
    float* out = (float*)d_out;

    // ws: h_a (83.89 MB) | h_b (83.89 MB) | weights (0.61 MB)  = 168.4 MB
    char* ws = (char*)d_ws;
    size_t SH = (size_t)NB1 * HS * sizeof(unsigned short);
    unsigned short* h_a = (unsigned short*)ws;
    unsigned short* h_b = (unsigned short*)(ws + SH);
    unsigned short* wb  = (unsigned short*)(ws + 2 * SH);
    unsigned short* WiP = wb;
    unsigned short* WhP = wb + 51200;
    unsigned short* WoA = wb + 153600;
    unsigned short* WoB = wb + 204800;

    dim3 blk(256);
    prep_w<<<1200, blk, 0, stream>>>(W_i, W_h, W_o, wb);
    bond_gemm<<<2049, blk, 0, stream>>>(fini, h_a, mapping, WiP, WhP, h_a, 0);
    bond_gemm<<<2049, blk, 0, stream>>>(fini, h_a, mapping, WiP, WhP, h_b, 1);
    bond_gemm<<<2049, blk, 0, stream>>>(fini, h_b, mapping, WiP, WhP, h_a, 1);
    atom_gemm<<<1024, blk, 0, stream>>>(atomf, h_a, a2b, WoA, WoB, b_o, out);
    copy_gf<<<NMOLS * (GFD / 4) / 256, blk, 0, stream>>>((const float4*)gf, out);
}

// Round 4
// 626.414 us; speedup vs baseline: 5.4947x; 1.0706x over previous
//
#include <hip/hip_runtime.h>

typedef short bf16x8 __attribute__((ext_vector_type(8)));
typedef float f32x4 __attribute__((ext_vector_type(4)));

constexpr int NB1    = 131073;   // num_bonds + 1 (row 131072 = zero sentinel)
constexpr int SENT   = 131072;
constexpr int NATOMS = 65536;
constexpr int AFD    = 133;
constexpr int CFD    = 147;
constexpr int DH     = 300;
constexpr int GFD    = 2048;
constexpr int NMOLS  = 4096;
constexpr int OUTD   = DH + GFD; // 2348
constexpr int HS     = 320;      // h row stride (bf16), also padded N
constexpr int KP1    = 160;      // padded CFD / AFD
constexpr int KP2    = 320;      // padded DH

__device__ __forceinline__ unsigned short f2b(float f) {
    unsigned u = __float_as_uint(f);
    u += 0x7fffu + ((u >> 16) & 1u);
    return (unsigned short)(u >> 16);
}
__device__ __forceinline__ unsigned pairsum4(unsigned a, unsigned b, unsigned c, unsigned d) {
    float lo = __uint_as_float(a << 16) + __uint_as_float(b << 16) +
               __uint_as_float(c << 16) + __uint_as_float(d << 16);
    float hi = __uint_as_float(a & 0xffff0000u) + __uint_as_float(b & 0xffff0000u) +
               __uint_as_float(c & 0xffff0000u) + __uint_as_float(d & 0xffff0000u);
    return ((unsigned)f2b(hi) << 16) | (unsigned)f2b(lo);
}
__device__ __forceinline__ bf16x8 asbf(uint4 u) {
    union { uint4 u; bf16x8 b; } c; c.u = u; return c.b;
}

// 20 MFMAs on chunk in As, B from registers
__device__ __forceinline__ void mfma_step(const short* __restrict__ A, const uint4 (&B)[5],
                                          int ml, int kl, f32x4 (&acc)[4][5]) {
    bf16x8 af[4];
#pragma unroll
    for (int mt = 0; mt < 4; ++mt)
        af[mt] = *(const bf16x8*)&A[(kl * 64 + mt * 16 + ml) * 8];
#pragma unroll
    for (int mt = 0; mt < 4; ++mt)
#pragma unroll
        for (int nt = 0; nt < 5; ++nt)
            acc[mt][nt] = __builtin_amdgcn_mfma_f32_16x16x32_bf16(af[mt], asbf(B[nt]), acc[mt][nt], 0, 0, 0);
}

// ---- bond GEMM: hdst = relu( fini@WiP^T  [+ (gather-sum_4 hsrc[mapping]) @ WhP^T] ) ----
__global__ __launch_bounds__(256, 2) void bond_gemm(
    const float* __restrict__ fini,           // [NB1][147] fp32
    const unsigned short* __restrict__ hsrc,  // [NB1][HS] bf16 bits
    const int* __restrict__ mapping,          // [NB1][4]
    const unsigned short* __restrict__ WiP,   // [320][160] bf16
    const unsigned short* __restrict__ WhP,   // [320][320] bf16
    unsigned short* __restrict__ hdst,        // [NB1][HS] bf16
    int do_msg)
{
    __shared__ __align__(16) short As[2][4 * 64 * 8];  // 2 x 4 KB
    __shared__ int idxs[64][4];
    const int tid  = threadIdx.x;
    const int m0   = blockIdx.x * 64;
    const int lane = tid & 63;
    const int w    = tid >> 6;
    const int ml   = lane & 15, kl = lane >> 4;
    const int sr   = tid & 63;   // staging row
    const int skh  = tid >> 6;   // staging k-half

    if (do_msg) {
        int r = tid >> 2, j = tid & 3;
        int m = m0 + r;
        int v = SENT;
        if (m < NB1) { int t = mapping[(size_t)m * 4 + j]; v = (t < 0) ? SENT : t; }
        idxs[r][j] = v;
    }
    __syncthreads();

    // per-thread gather base pointers (+ skh*8 element offset baked in)
    int i0 = SENT, i1 = SENT, i2 = SENT, i3 = SENT;
    if (do_msg) { i0 = idxs[sr][0]; i1 = idxs[sr][1]; i2 = idxs[sr][2]; i3 = idxs[sr][3]; }
    const unsigned short* g0 = hsrc + (size_t)i0 * HS + skh * 8;
    const unsigned short* g1 = hsrc + (size_t)i1 * HS + skh * 8;
    const unsigned short* g2 = hsrc + (size_t)i2 * HS + skh * 8;
    const unsigned short* g3 = hsrc + (size_t)i3 * HS + skh * 8;
    // per-thread B fragment row pointers
    const unsigned short* bWi = WiP + (size_t)(w * 80 + ml) * KP1 + kl * 8;
    const unsigned short* bWh = WhP + (size_t)(w * 80 + ml) * KP2 + kl * 8;
    const float* fp = fini + (size_t)(m0 + sr) * CFD;
    const bool mok = (m0 + sr) < NB1;

    f32x4 acc[4][5];
#pragma unroll
    for (int mt = 0; mt < 4; ++mt)
#pragma unroll
        for (int nt = 0; nt < 5; ++nt) acc[mt][nt] = (f32x4){0.f, 0.f, 0.f, 0.f};

    const int nch = do_msg ? 15 : 5;   // chunks 0..4 = fini phase, 5..14 = gather phase

    // ---- stage chunk 0 (fini, k<32 so no k-guard) + Bcur chunk 0 ----
    {
        union { short s[8]; bf16x8 x; } u;
#pragma unroll
        for (int j = 0; j < 8; ++j) {
            float v = mok ? fp[skh * 8 + j] : 0.f;
            u.s[j] = (short)f2b(v);
        }
        *(bf16x8*)&As[0][(skh * 64 + sr) * 8] = u.x;
    }
    uint4 Bcur[5];
#pragma unroll
    for (int nt = 0; nt < 5; ++nt) Bcur[nt] = *(const uint4*)(bWi + nt * 16 * KP1);
    __syncthreads();

    for (int c = 0; c < nch; ++c) {
        const int cn = c + 1;
        const bool havenext = cn < nch;
        const bool nfini = cn < 5;
        float vn[8];
        uint4 ga, gb, gc, gd;
        uint4 Bnxt[5];
        if (havenext) {
            if (nfini) {
                int kb = cn * 32 + skh * 8;
#pragma unroll
                for (int j = 0; j < 8; ++j) {
                    int k = kb + j;
                    vn[j] = (mok && k < CFD) ? fp[k] : 0.f;
                }
#pragma unroll
                for (int nt = 0; nt < 5; ++nt)
                    Bnxt[nt] = *(const uint4*)(bWi + cn * 32 + nt * 16 * KP1);
            } else {
                int koff = (cn - 5) * 32;
                ga = *(const uint4*)(g0 + koff);
                gb = *(const uint4*)(g1 + koff);
                gc = *(const uint4*)(g2 + koff);
                gd = *(const uint4*)(g3 + koff);
#pragma unroll
                for (int nt = 0; nt < 5; ++nt)
                    Bnxt[nt] = *(const uint4*)(bWh + (cn - 5) * 32 + nt * 16 * KP2);
            }
        }

        mfma_step(As[c & 1], Bcur, ml, kl, acc);

        if (havenext) {
            short* A = As[cn & 1];
            if (nfini) {
                union { short s[8]; bf16x8 x; } u;
#pragma unroll
                for (int j = 0; j < 8; ++j) u.s[j] = (short)f2b(vn[j]);
                *(bf16x8*)&A[(skh * 64 + sr) * 8] = u.x;
            } else {
                uint4 o;
                o.x = pairsum4(ga.x, gb.x, gc.x, gd.x);
                o.y = pairsum4(ga.y, gb.y, gc.y, gd.y);
                o.z = pairsum4(ga.z, gb.z, gc.z, gd.z);
                o.w = pairsum4(ga.w, gb.w, gc.w, gd.w);
                *(uint4*)&A[(skh * 64 + sr) * 8] = o;
            }
#pragma unroll
            for (int nt = 0; nt < 5; ++nt) Bcur[nt] = Bnxt[nt];
        }
        __syncthreads();
    }

    // ---- epilogue: relu -> bf16, write all 320 cols (pad cols get relu(0)=0) ----
#pragma unroll
    for (int mt = 0; mt < 4; ++mt) {
#pragma unroll
        for (int reg = 0; reg < 4; ++reg) {
            int mm = m0 + mt * 16 + kl * 4 + reg;
            if (mm < NB1) {
#pragma unroll
                for (int nt = 0; nt < 5; ++nt) {
                    int n = w * 80 + nt * 16 + ml;
                    float v = acc[mt][nt][reg];
                    hdst[(size_t)mm * HS + n] = f2b(v > 0.f ? v : 0.f);
                }
            }
        }
    }
}

// ---- atom GEMM + fused molecule mean ----
__global__ __launch_bounds__(256, 2) void atom_gemm(
    const float* __restrict__ atomf,          // [NATOMS][133] fp32
    const unsigned short* __restrict__ hsrc,  // [NB1][HS] bf16
    const int* __restrict__ a2b,              // [NATOMS][4]
    const unsigned short* __restrict__ WoA,   // [320][160] bf16 (Wo cols 0..132)
    const unsigned short* __restrict__ WoB,   // [320][320] bf16 (Wo cols 133..432)
    const float* __restrict__ bo,             // [300]
    float* __restrict__ out)                  // [NMOLS][OUTD]
{
    __shared__ __align__(16) short As[2][4 * 64 * 8];
    __shared__ int idxs[64][4];
    const int tid  = threadIdx.x;
    const int m0   = blockIdx.x * 64;
    const int lane = tid & 63;
    const int w    = tid >> 6;
    const int ml   = lane & 15, kl = lane >> 4;
    const int sr   = tid & 63;
    const int skh  = tid >> 6;

    {
        int r = tid >> 2, j = tid & 3;
        int t = a2b[(size_t)(m0 + r) * 4 + j];
        idxs[r][j] = (t < 0) ? SENT : t;
    }
    __syncthreads();

    const int i0 = idxs[sr][0], i1 = idxs[sr][1], i2 = idxs[sr][2], i3 = idxs[sr][3];
    const unsigned short* g0 = hsrc + (size_t)i0 * HS + skh * 8;
    const unsigned short* g1 = hsrc + (size_t)i1 * HS + skh * 8;
    const unsigned short* g2 = hsrc + (size_t)i2 * HS + skh * 8;
    const unsigned short* g3 = hsrc + (size_t)i3 * HS + skh * 8;
    const unsigned short* bWa = WoA + (size_t)(w * 80 + ml) * KP1 + kl * 8;
    const unsigned short* bWb = WoB + (size_t)(w * 80 + ml) * KP2 + kl * 8;
    const float* fp = atomf + (size_t)(m0 + sr) * AFD;

    f32x4 acc[4][5];
#pragma unroll
    for (int mt = 0; mt < 4; ++mt)
#pragma unroll
        for (int nt = 0; nt < 5; ++nt) acc[mt][nt] = (f32x4){0.f, 0.f, 0.f, 0.f};

    {
        union { short s[8]; bf16x8 x; } u;
#pragma unroll
        for (int j = 0; j < 8; ++j) u.s[j] = (short)f2b(fp[skh * 8 + j]);
        *(bf16x8*)&As[0][(skh * 64 + sr) * 8] = u.x;
    }
    uint4 Bcur[5];
#pragma unroll
    for (int nt = 0; nt < 5; ++nt) Bcur[nt] = *(const uint4*)(bWa + nt * 16 * KP1);
    __syncthreads();

    for (int c = 0; c < 15; ++c) {
        const int cn = c + 1;
        const bool havenext = cn < 15;
        const bool nfini = cn < 5;
        float vn[8];
        uint4 ga, gb, gc, gd;
        uint4 Bnxt[5];
        if (havenext) {
            if (nfini) {
                int kb = cn * 32 + skh * 8;
#pragma unroll
                for (int j = 0; j < 8; ++j) {
                    int k = kb + j;
                    vn[j] = (k < AFD) ? fp[k] : 0.f;
                }
#pragma unroll
                for (int nt = 0; nt < 5; ++nt)
                    Bnxt[nt] = *(const uint4*)(bWa + cn * 32 + nt * 16 * KP1);
            } else {
                int koff = (cn - 5) * 32;
                ga = *(const uint4*)(g0 + koff);
                gb = *(const uint4*)(g1 + koff);
                gc = *(const uint4*)(g2 + koff);
                gd = *(const uint4*)(g3 + koff);
#pragma unroll
                for (int nt = 0; nt < 5; ++nt)
                    Bnxt[nt] = *(const uint4*)(bWb + (cn - 5) * 32 + nt * 16 * KP2);
            }
        }

        mfma_step(As[c & 1], Bcur, ml, kl, acc);

        if (havenext) {
            short* A = As[cn & 1];
            if (nfini) {
                union { short s[8]; bf16x8 x; } u;
#pragma unroll
                for (int j = 0; j < 8; ++j) u.s[j] = (short)f2b(vn[j]);
                *(bf16x8*)&A[(skh * 64 + sr) * 8] = u.x;
            } else {
                uint4 o;
                o.x = pairsum4(ga.x, gb.x, gc.x, gd.x);
                o.y = pairsum4(ga.y, gb.y, gc.y, gd.y);
                o.z = pairsum4(ga.z, gb.z, gc.z, gd.z);
                o.w = pairsum4(ga.w, gb.w, gc.w, gd.w);
                *(uint4*)&A[(skh * 64 + sr) * 8] = o;
            }
#pragma unroll
            for (int nt = 0; nt < 5; ++nt) Bcur[nt] = Bnxt[nt];
        }
        __syncthreads();
    }

    // ---- epilogue: bias + relu + 16-row (one molecule per m-tile) mean -> out ----
#pragma unroll
    for (int mt = 0; mt < 4; ++mt) {
        int mol = blockIdx.x * 4 + mt;
#pragma unroll
        for (int nt = 0; nt < 5; ++nt) {
            int n = w * 80 + nt * 16 + ml;
            float bias = (n < DH) ? bo[n] : 0.f;
            float s = 0.f;
#pragma unroll
            for (int reg = 0; reg < 4; ++reg) {
                float v = acc[mt][nt][reg] + bias;
                s += (v > 0.f ? v : 0.f);
            }
            s += __shfl_down(s, 32, 64);
            s += __shfl_down(s, 16, 64);
            if (kl == 0 && n < DH) out[(size_t)mol * OUTD + n] = s * (1.f / 16.f);
        }
    }
}

// ---- weight prep: fp32 -> padded bf16 ----
__global__ void prep_w(const float* __restrict__ Wi, const float* __restrict__ Wh,
                       const float* __restrict__ Wo, unsigned short* __restrict__ wb) {
    int t = blockIdx.x * blockDim.x + threadIdx.x;
    if (t >= 307200) return;
    float v = 0.f;
    if (t < 51200) {                       // WiP [320][160]
        int n = t / 160, k = t % 160;
        if (n < DH && k < CFD) v = Wi[n * CFD + k];
    } else if (t < 153600) {               // WhP [320][320]
        int q = t - 51200; int n = q / 320, k = q % 320;
        if (n < DH && k < DH) v = Wh[n * DH + k];
    } else if (t < 204800) {               // WoA [320][160]
        int q = t - 153600; int n = q / 160, k = q % 160;
        if (n < DH && k < AFD) v = Wo[n * 433 + k];
    } else {                               // WoB [320][320]
        int q = t - 204800; int n = q / 320, k = q % 320;
        if (n < DH && k < DH) v = Wo[n * 433 + AFD + k];
    }
    wb[t] = f2b(v);
}

// ---- copy global features: out[mol][300:2348] = gf[mol] ----
__global__ void copy_gf(const float4* __restrict__ gf, float* __restrict__ out) {
    int t = blockIdx.x * blockDim.x + threadIdx.x;
    if (t >= NMOLS * (GFD / 4)) return;
    int mol = t >> 9;
    int g4 = t & 511;
    float4 v = gf[t];
    *(float4*)(out + (size_t)mol * OUTD + DH + g4 * 4) = v;
}

extern "C" void kernel_launch(void* const* d_in, const int* in_sizes, int n_in,
                              void* d_out, int out_size, void* d_ws, size_t ws_size,
                              hipStream_t stream) {
    const float* atomf   = (const float*)d_in[0];
    const float* fini    = (const float*)d_in[1];
    const int*   a2b     = (const int*)d_in[2];
    const int*   mapping = (const int*)d_in[3];
    const float* gf      = (const float*)d_in[4];
    const float* W_i     = (const float*)d_in[5];
    const float* W_h     = (const float*)d_in[6];
    const float* W_o     = (const float*)d_in[7];
    const float* b_o     = (const float*)d_in[8];
    float* out = (float*)d_out;

    // ws: h_a (83.89 MB) | h_b (83.89 MB) | weights (0.61 MB) = 168.4 MB
    char* ws = (char*)d_ws;
    size_t SH = (size_t)NB1 * HS * sizeof(unsigned short);
    unsigned short* h_a = (unsigned short*)ws;
    unsigned short* h_b = (unsigned short*)(ws + SH);
    unsigned short* wb  = (unsigned short*)(ws + 2 * SH);
    unsigned short* WiP = wb;
    unsigned short* WhP = wb + 51200;
    unsigned short* WoA = wb + 153600;
    unsigned short* WoB = wb + 204800;

    dim3 blk(256);
    prep_w<<<1200, blk, 0, stream>>>(W_i, W_h, W_o, wb);
    bond_gemm<<<2049, blk, 0, stream>>>(fini, h_a, mapping, WiP, WhP, h_a, 0);
    bond_gemm<<<2049, blk, 0, stream>>>(fini, h_a, mapping, WiP, WhP, h_b, 1);
    bond_gemm<<<2049, blk, 0, stream>>>(fini, h_b, mapping, WiP, WhP, h_a, 1);
    atom_gemm<<<1024, blk, 0, stream>>>(atomf, h_a, a2b, WoA, WoB, b_o, out);
    copy_gf<<<NMOLS * (GFD / 4) / 256, blk, 0, stream>>>((const float4*)gf, out);
}